// Round 1
// baseline (85433.075 us; speedup 1.0000x reference)
//
#include <hip/hip_runtime.h>
#include <cstdint>
#include <cstddef>

#define T_ 256
#define B_ 64
#define H_ 768
#define H2_ 1536
#define H3_ 2304
#define H4_ 3072
#define NBLK 256
#define NTHR 256
#define GRIDTH (NBLK*NTHR)

typedef __attribute__((ext_vector_type(8))) short short8;
typedef __attribute__((ext_vector_type(4))) float f4;

struct Params {
  const float* question; const float* answer; float* x; const int* ping;
  const float* h0; const float* c0;
  const float* Wqh; const float* bqh; const float* Wah; const float* bah;
  const float* Wih; const float* bih; const float* Whh; const float* bhh;
  const float* Wq;  const float* bq;  const float* Wk;  const float* bk;
  const float* Wv;  const float* bv;  const float* Wfuse; const float* bfuse;
  float* out;
  unsigned* flags; unsigned* gen;
  unsigned short* Wqkv_s; unsigned short* Wfuse_s; unsigned short* Wih_s; unsigned short* Whh_s;
  unsigned short* pairX; unsigned short* ctxb; unsigned short* newvb; unsigned short* hB;
  float* base; float* qkvbuf; float* gatesH; float* cbuf;
};

__device__ __forceinline__ unsigned short f2b(float f){
  union { float f; unsigned u; } a; a.f = f;
  unsigned u = a.u;
  unsigned r = u + 0x7FFFu + ((u >> 16) & 1u);
  return (unsigned short)(r >> 16);
}

__device__ __forceinline__ float sigm(float x){ return 1.0f/(1.0f+__expf(-x)); }
__device__ __forceinline__ float tanh_(float x){ return 2.0f/(1.0f+__expf(-2.0f*x)) - 1.0f; }

__device__ __forceinline__ f4 mfma16(short8 a, short8 b, f4 c){
  return __builtin_amdgcn_mfma_f32_16x16x32_bf16(a, b, c, 0, 0, 0);
}

__device__ __forceinline__ float wsum(float x){
  #pragma unroll
  for (int off = 32; off > 0; off >>= 1) x += __shfl_xor(x, off, 64);
  return x;
}

// grid barrier: per-block flag (release) + block-0 aggregator bumps gen.
__device__ __forceinline__ void gsync(unsigned* flags, unsigned* gen, unsigned e){
  __threadfence();
  __syncthreads();
  if (threadIdx.x == 0)
    __hip_atomic_store(flags + blockIdx.x, e, __ATOMIC_RELEASE, __HIP_MEMORY_SCOPE_AGENT);
  if (blockIdx.x == 0){
    while (__hip_atomic_load(flags + threadIdx.x, __ATOMIC_RELAXED, __HIP_MEMORY_SCOPE_AGENT) < e)
      __builtin_amdgcn_s_sleep(1);
    __threadfence();
    __syncthreads();
    if (threadIdx.x == 0)
      __hip_atomic_store(gen, e, __ATOMIC_RELEASE, __HIP_MEMORY_SCOPE_AGENT);
  }
  if (threadIdx.x == 0){
    while (__hip_atomic_load(gen, __ATOMIC_RELAXED, __HIP_MEMORY_SCOPE_AGENT) < e)
      __builtin_amdgcn_s_sleep(1);
  }
  __syncthreads();
  __threadfence();   // acquire side for every thread
}

// generic fp32 -> bf16 MFMA-B swizzle: group (kb,nb) of 512 elems; lane l holds
// B[kb*32 + (l>>4)*8 + j][nb*16 + (l&15)], j=0..7 contiguous.
__device__ __forceinline__ void swz(const float* src, unsigned short* dst, int K, int N, int tid){
  const int NB = N >> 4;
  const long long E8 = ((long long)K * N) >> 3;
  for (long long e = tid; e < E8; e += GRIDTH){
    int g = (int)(e >> 6), l = (int)(e & 63);
    int kb = g / NB, nb = g - kb*NB;
    int k0 = kb*32 + ((l >> 4) << 3);
    int n  = nb*16 + (l & 15);
    union { unsigned short u[8]; short8 v; } t8;
    #pragma unroll
    for (int j = 0; j < 8; j++) t8.u[j] = f2b(src[(long long)(k0 + j) * N + n]);
    *(short8*)(dst + (e << 3)) = t8.v;
  }
}

__launch_bounds__(NTHR, 1)
__global__ void sqac_kernel(Params p){
  const int tid  = blockIdx.x * NTHR + threadIdx.x;
  const int lane = threadIdx.x & 63;
  const int wid  = tid >> 6;               // global wave id 0..1023
  const int c16  = lane & 15, q4 = lane >> 4;
  unsigned e = 0;

  // ================= P0: setup =================
  {
    // Wqkv swizzle (Wq|Wk|Wv columns concatenated, N=2304)
    const long long E8 = ((long long)H_ * H3_) >> 3;
    for (long long ee = tid; ee < E8; ee += GRIDTH){
      int g = (int)(ee >> 6), l = (int)(ee & 63);
      int kb = g / 144, nb = g - kb*144;
      int k0 = kb*32 + ((l >> 4) << 3);
      int n  = nb*16 + (l & 15);
      const float* s; int nn;
      if (n < H_)      { s = p.Wq; nn = n; }
      else if (n < H2_){ s = p.Wk; nn = n - H_; }
      else             { s = p.Wv; nn = n - H2_; }
      union { unsigned short u[8]; short8 v; } t8;
      #pragma unroll
      for (int j = 0; j < 8; j++) t8.u[j] = f2b(s[(long long)(k0 + j) * H_ + nn]);
      *(short8*)(p.Wqkv_s + (ee << 3)) = t8.v;
    }
    swz(p.Wfuse, p.Wfuse_s, H2_, H_,  tid);
    swz(p.Wih,   p.Wih_s,   H_,  H4_, tid);
    swz(p.Whh,   p.Whh_s,   H_,  H4_, tid);

    // base = q@Wqh + bqh + a@Wah + bah + bih + bhh  (fp32, once per launch)
    if (tid < 49152){
      const int n  = tid % H4_;
      const int b0 = (tid / H4_) * 4;
      const float bias = p.bqh[n] + p.bah[n] + p.bih[n] + p.bhh[n];
      float a0 = bias, a1 = bias, a2 = bias, a3 = bias;
      for (int k = 0; k < H_; k++){
        const float wq = p.Wqh[(long long)k*H4_ + n];
        const float wa = p.Wah[(long long)k*H4_ + n];
        a0 += p.question[(b0+0)*H_+k]*wq + p.answer[(b0+0)*H_+k]*wa;
        a1 += p.question[(b0+1)*H_+k]*wq + p.answer[(b0+1)*H_+k]*wa;
        a2 += p.question[(b0+2)*H_+k]*wq + p.answer[(b0+2)*H_+k]*wa;
        a3 += p.question[(b0+3)*H_+k]*wq + p.answer[(b0+3)*H_+k]*wa;
      }
      p.base[(b0+0)*H4_+n] = a0; p.base[(b0+1)*H4_+n] = a1;
      p.base[(b0+2)*H4_+n] = a2; p.base[(b0+3)*H4_+n] = a3;
    }

    // pairX for t=0 (rows 0..63 = left, 64..127 = right)
    for (int ee = tid; ee < 128*H_; ee += GRIDTH){
      int m = ee / H_, k = ee - m*H_;
      int b = m & 63;
      int st;
      if (m < 64){ int pt = p.ping[b*T_]; st = pt - 1; st = st < 0 ? 0 : (st > T_-1 ? T_-1 : st); }
      else st = 0;
      p.pairX[ee] = f2b(p.x[(long long)(st*B_ + b)*H_ + k]);
    }
    // h, c init
    for (int ee = tid; ee < B_*H_; ee += GRIDTH){
      p.hB[ee]   = f2b(p.h0[ee]);
      p.cbuf[ee] = p.c0[ee];
    }
  }
  e++; gsync(p.flags, p.gen, e);

  // ================= main scan =================
  for (int t = 0; t < T_; t++){

    // ---- P1: qkv = pairX @ Wqkv (+bias)  and  gatesH = h @ Whh ----
    if (wid < 288){
      const int nt = wid >> 1, mh = wid & 1;
      f4 z = {0.f,0.f,0.f,0.f};
      f4 acc0=z, acc1=z, acc2=z, acc3=z;
      const unsigned short* A  = p.pairX + (mh*64 + c16)*H_ + q4*8;
      const unsigned short* Bp = p.Wqkv_s + lane*8 + ((long long)nt << 9);
      for (int kb = 0; kb < 24; kb++){
        short8 bf = *(const short8*)(Bp + ((long long)(kb*144) << 9));
        const unsigned short* ap = A + kb*32;
        acc0 = mfma16(*(const short8*)(ap         ), bf, acc0);
        acc1 = mfma16(*(const short8*)(ap + 16*H_ ), bf, acc1);
        acc2 = mfma16(*(const short8*)(ap + 32*H_ ), bf, acc2);
        acc3 = mfma16(*(const short8*)(ap + 48*H_ ), bf, acc3);
      }
      const int n = nt*16 + c16;
      const float bias = (n < H_) ? p.bq[n] : (n < H2_ ? p.bk[n - H_] : p.bv[n - H2_]);
      float* op = p.qkvbuf + (long long)(mh*64 + q4*4)*H3_ + n;
      f4 av[4] = {acc0, acc1, acc2, acc3};
      #pragma unroll
      for (int mt = 0; mt < 4; mt++)
        #pragma unroll
        for (int r = 0; r < 4; r++)
          op[(mt*16 + r)*H3_] = av[mt][r] + bias;
    } else if (wid < 480){
      const int nt = wid - 288;
      f4 z = {0.f,0.f,0.f,0.f};
      f4 acc0=z, acc1=z, acc2=z, acc3=z;
      const unsigned short* A  = p.hB + c16*H_ + q4*8;
      const unsigned short* Bp = p.Whh_s + lane*8 + ((long long)nt << 9);
      for (int kb = 0; kb < 24; kb++){
        short8 bf = *(const short8*)(Bp + ((long long)(kb*192) << 9));
        const unsigned short* ap = A + kb*32;
        acc0 = mfma16(*(const short8*)(ap         ), bf, acc0);
        acc1 = mfma16(*(const short8*)(ap + 16*H_ ), bf, acc1);
        acc2 = mfma16(*(const short8*)(ap + 32*H_ ), bf, acc2);
        acc3 = mfma16(*(const short8*)(ap + 48*H_ ), bf, acc3);
      }
      const int n = nt*16 + c16;
      float* op = p.gatesH + (long long)(q4*4)*H4_ + n;
      f4 av[4] = {acc0, acc1, acc2, acc3};
      #pragma unroll
      for (int mt = 0; mt < 4; mt++)
        #pragma unroll
        for (int r = 0; r < 4; r++)
          op[(mt*16 + r)*H4_] = av[mt][r];
    }
    e++; gsync(p.flags, p.gen, e);

    // ---- P2: tiny 2-token attention per (b, head) ----
    if (wid < 768){
      const int b = wid / 12, h = wid - b*12;
      const int rowl = b*H3_, rowr = (64 + b)*H3_;
      const int off = h*64 + lane;
      const float* qk = p.qkvbuf;
      float ql = qk[rowl + off],        qr = qk[rowr + off];
      float kl = qk[rowl + H_  + off],  kr = qk[rowr + H_  + off];
      float vl = qk[rowl + H2_ + off],  vr = qk[rowr + H2_ + off];
      float sll = wsum(ql*kl)*0.125f;
      float slr = wsum(ql*kr)*0.125f;
      float srl = wsum(qr*kl)*0.125f;
      float srr = wsum(qr*kr)*0.125f;
      float ml = fmaxf(sll, slr), mr = fmaxf(srl, srr);
      float ell = __expf(sll-ml), elr = __expf(slr-ml);
      float erl = __expf(srl-mr), err = __expf(srr-mr);
      float il = 1.0f/(ell+elr), ir = 1.0f/(erl+err);
      float cl = (ell*il)*vl + (elr*il)*vr;
      float cr = (erl*ir)*vl + (err*ir)*vr;
      p.ctxb[b*H2_ + h*64 + lane]      = f2b(cl);
      p.ctxb[b*H2_ + H_ + h*64 + lane] = f2b(cr);
    }
    e++; gsync(p.flags, p.gen, e);

    // ---- P3: fused = ctx @ Wfuse + bfuse; newv select; update inputs[t] ----
    if (wid < 48){
      const int nt = wid;
      f4 z = {0.f,0.f,0.f,0.f};
      f4 acc0=z, acc1=z, acc2=z, acc3=z;
      const unsigned short* A  = p.ctxb + c16*H2_ + q4*8;
      const unsigned short* Bp = p.Wfuse_s + lane*8 + ((long long)nt << 9);
      for (int kb = 0; kb < 48; kb++){
        short8 bf = *(const short8*)(Bp + ((long long)(kb*48) << 9));
        const unsigned short* ap = A + kb*32;
        acc0 = mfma16(*(const short8*)(ap          ), bf, acc0);
        acc1 = mfma16(*(const short8*)(ap + 16*H2_ ), bf, acc1);
        acc2 = mfma16(*(const short8*)(ap + 32*H2_ ), bf, acc2);
        acc3 = mfma16(*(const short8*)(ap + 48*H2_ ), bf, acc3);
      }
      const int n = nt*16 + c16;
      const float bias = p.bfuse[n];
      f4 av[4] = {acc0, acc1, acc2, acc3};
      #pragma unroll
      for (int mt = 0; mt < 4; mt++)
        #pragma unroll
        for (int r = 0; r < 4; r++){
          const int b = mt*16 + q4*4 + r;
          const float f = av[mt][r] + bias;
          const int pt = p.ping[b*T_ + t];
          const bool cond = (pt > 0) && (t > 0);
          const long long xi = (long long)(t*B_ + b)*H_ + n;
          float val;
          if (cond){ p.x[xi] = f; val = f; }
          else     { val = p.x[xi]; }
          p.newvb[b*H_ + n] = f2b(val);
        }
    }
    e++; gsync(p.flags, p.gen, e);

    // ---- P4: gates = base + gatesH + newv@Wih; LSTM elementwise; gather next pair ----
    if (wid < 48){
      const int jt = wid;
      f4 z = {0.f,0.f,0.f,0.f};
      f4 acc[4][4];   // [gate][mtile]
      #pragma unroll
      for (int g = 0; g < 4; g++)
        #pragma unroll
        for (int mt = 0; mt < 4; mt++) acc[g][mt] = z;
      const unsigned short* A = p.newvb + c16*H_ + q4*8;
      for (int kb = 0; kb < 24; kb++){
        short8 bfr[4];
        #pragma unroll
        for (int g = 0; g < 4; g++)
          bfr[g] = *(const short8*)(p.Wih_s + ((long long)(kb*192 + g*48 + jt) << 9) + lane*8);
        const unsigned short* ap = A + kb*32;
        #pragma unroll
        for (int mt = 0; mt < 4; mt++){
          short8 af = *(const short8*)(ap + mt*16*H_);
          #pragma unroll
          for (int g = 0; g < 4; g++) acc[g][mt] = mfma16(af, bfr[g], acc[g][mt]);
        }
      }
      const int j = jt*16 + c16;
      #pragma unroll
      for (int mt = 0; mt < 4; mt++)
        #pragma unroll
        for (int r = 0; r < 4; r++){
          const int b  = mt*16 + q4*4 + r;
          const int bh = b*H4_;
          const float iv = acc[0][mt][r] + p.base[bh + j]        + p.gatesH[bh + j];
          const float fv = acc[1][mt][r] + p.base[bh + H_  + j]  + p.gatesH[bh + H_  + j];
          const float gv = acc[2][mt][r] + p.base[bh + H2_ + j]  + p.gatesH[bh + H2_ + j];
          const float ov = acc[3][mt][r] + p.base[bh + H3_ + j]  + p.gatesH[bh + H3_ + j];
          const float co = p.cbuf[b*H_ + j];
          const float cn = sigm(fv)*co + sigm(iv)*tanh_(gv);
          const float hh = sigm(ov)*tanh_(cn);
          p.out[(long long)(t*B_ + b)*H_ + j] = hh;
          p.hB[b*H_ + j]   = f2b(hh);
          p.cbuf[b*H_ + j] = cn;
          if (t == T_-1){
            p.out[12582912 + b*H_ + j]         = hh;  // hT
            p.out[12582912 + 49152 + b*H_ + j] = cn;  // cT
          }
        }
    } else if (wid >= 512 && wid < 640){
      if (t + 1 < T_){
        const int m = wid - 512;        // 0..127
        const int b = m & 63;
        int st;
        if (m < 64){
          int pt = p.ping[b*T_ + (t+1)];
          st = pt - 1; st = st < 0 ? 0 : (st > T_-1 ? T_-1 : st);
        } else st = t + 1;
        const float* src = p.x + (long long)(st*B_ + b)*H_;
        unsigned short* dst = p.pairX + m*H_;
        for (int k = lane; k < H_; k += 64) dst[k] = f2b(src[k]);
      }
    }
    e++; gsync(p.flags, p.gen, e);
  }
}

extern "C" void kernel_launch(void* const* d_in, const int* in_sizes, int n_in,
                              void* d_out, int out_size, void* d_ws, size_t ws_size,
                              hipStream_t stream)
{
  (void)in_sizes; (void)n_in; (void)out_size; (void)ws_size;
  char* ws = (char*)d_ws;
  size_t off = 0;
  auto take = [&](size_t bytes)->void*{
    void* ptr = ws + off;
    off += (bytes + 255) & ~(size_t)255;
    return ptr;
  };

  Params p;
  p.question = (const float*)d_in[0];
  p.answer   = (const float*)d_in[1];
  p.x        = (float*)d_in[2];          // mutable inputs buffer (restored by harness each launch)
  p.ping     = (const int*)d_in[3];
  p.h0  = (const float*)d_in[4];  p.c0  = (const float*)d_in[5];
  p.Wqh = (const float*)d_in[6];  p.bqh = (const float*)d_in[7];
  p.Wah = (const float*)d_in[8];  p.bah = (const float*)d_in[9];
  p.Wih = (const float*)d_in[10]; p.bih = (const float*)d_in[11];
  p.Whh = (const float*)d_in[12]; p.bhh = (const float*)d_in[13];
  p.Wq  = (const float*)d_in[14]; p.bq  = (const float*)d_in[15];
  p.Wk  = (const float*)d_in[16]; p.bk  = (const float*)d_in[17];
  p.Wv  = (const float*)d_in[18]; p.bv  = (const float*)d_in[19];
  p.Wfuse = (const float*)d_in[20]; p.bfuse = (const float*)d_in[21];
  p.out = (float*)d_out;

  unsigned* sync = (unsigned*)take(2048);
  p.flags = sync;
  p.gen   = sync + 256;

  p.Wqkv_s  = (unsigned short*)take((size_t)H_ *H3_*2);
  p.Wfuse_s = (unsigned short*)take((size_t)H2_*H_ *2);
  p.Wih_s   = (unsigned short*)take((size_t)H_ *H4_*2);
  p.Whh_s   = (unsigned short*)take((size_t)H_ *H4_*2);
  p.pairX   = (unsigned short*)take((size_t)128*H_*2);
  p.ctxb    = (unsigned short*)take((size_t)B_*H2_*2);
  p.newvb   = (unsigned short*)take((size_t)B_*H_*2);
  p.hB      = (unsigned short*)take((size_t)B_*H_*2);
  p.base    = (float*)take((size_t)B_*H4_*4);
  p.qkvbuf  = (float*)take((size_t)128*H3_*4);
  p.gatesH  = (float*)take((size_t)B_*H4_*4);
  p.cbuf    = (float*)take((size_t)B_*H_*4);

  hipMemsetAsync(sync, 0, 2048, stream);
  hipLaunchKernelGGL(sqac_kernel, dim3(NBLK), dim3(NTHR), 0, stream, p);
}

// Round 3
// 28205.423 us; speedup vs baseline: 3.0290x; 3.0290x over previous
//
#include <hip/hip_runtime.h>
#include <cstdint>
#include <cstddef>

// SQACILSTM round 3: same structure as round 2 (persistent 72-block kernel,
// 2 fence-free grid barriers per step, all cross-block data via agent-scope
// relaxed atomics -> coherent LLC). Fix: LDS A-tile loaders staged only HALF
// of each row (u64-slot count miscomputed); afrag then read uninit LDS -> NaN.
// PA loader i<24 -> i<48; gatesHX i<12 -> i<24 (both halves); PB i<24 -> i<48.

#define T_   256
#define B_   64
#define NBLK 72
#define NTHR 256
#define GRIDTH (NBLK*NTHR)
#define HALL 12582912   // 256*64*768

typedef __attribute__((ext_vector_type(8))) short short8;
typedef __attribute__((ext_vector_type(4))) float f4;
typedef unsigned long long u64t;
typedef unsigned short u16t;
typedef unsigned int u32t;

struct Params {
  const float* question; const float* answer; float* x; const int* ping;
  const float* h0; const float* c0;
  const float* Wqh; const float* bqh; const float* Wah; const float* bah;
  const float* Wih; const float* bih; const float* Whh; const float* bhh;
  const float* Wq;  const float* bq;  const float* Wk;  const float* bk;
  const float* Wv;  const float* bv;  const float* Wfuse; const float* bfuse;
  float* out;
  u32t* flags; u32t* gen;
  u16t* Wqkv_s;    // per-head swizzled [12][24][12][64][8]
  u16t* Whhih_s;   // vstack(Whh,Wih) swizzled K=1536,N=3072
  u16t* Wfuse_s;   // swizzled K=1536,N=768
  u16t* Wcomb_s;   // Wfuse@Wih swizzled K=1536,N=3072
  u16t* Wfuse_bf;  // row-major bf16 Wfuse [1536][768]
  float* base;     // [64][3072]
  float* gatesHX;  // [64][3072]  (h@Whh + masked_x@Wih)
  u16t* ctxb;      // [64][1536] bf16
  u16t* hB;        // [64][768] bf16
  float* cbuf;     // [64][768]
  float* bfW;      // [3072] = bfuse @ Wih
};

__device__ __forceinline__ u16t f2b(float f){
  union { float f; u32t u; } a; a.f = f;
  u32t u = a.u;
  u32t r = u + 0x7FFFu + ((u >> 16) & 1u);
  return (u16t)(r >> 16);
}
__device__ __forceinline__ float b2f(u16t u){
  union { u32t u; float f; } a; a.u = ((u32t)u) << 16; return a.f;
}
__device__ __forceinline__ u64t pack4u(u64t s0, u64t s1){
  union { u64t v; float f[2]; } a, b; a.v = s0; b.v = s1;
  return (u64t)f2b(a.f[0]) | ((u64t)f2b(a.f[1])<<16) |
         ((u64t)f2b(b.f[0])<<32) | ((u64t)f2b(b.f[1])<<48);
}
__device__ __forceinline__ u64t pack4f(float a, float b, float c, float d){
  return (u64t)f2b(a) | ((u64t)f2b(b)<<16) | ((u64t)f2b(c)<<32) | ((u64t)f2b(d)<<48);
}
__device__ __forceinline__ float sigm(float x){ return 1.0f/(1.0f+__expf(-x)); }
__device__ __forceinline__ float tanh_(float x){ return 2.0f/(1.0f+__expf(-2.0f*x)) - 1.0f; }
__device__ __forceinline__ f4 mfma16(short8 a, short8 b, f4 c){
  return __builtin_amdgcn_mfma_f32_16x16x32_bf16(a, b, c, 0, 0, 0);
}
__device__ __forceinline__ float wsum(float x){
  #pragma unroll
  for (int off = 32; off > 0; off >>= 1) x += __shfl_xor(x, off, 64);
  return x;
}

// ---- coherent (LLC, L2-bypassing) access helpers ----
__device__ __forceinline__ u64t cld64(const void* p){
  return __hip_atomic_load((const u64t*)p, __ATOMIC_RELAXED, __HIP_MEMORY_SCOPE_AGENT);
}
__device__ __forceinline__ float cldf(const float* p){
  return __hip_atomic_load(p, __ATOMIC_RELAXED, __HIP_MEMORY_SCOPE_AGENT);
}
__device__ __forceinline__ void cstf(float* p, float v){
  __hip_atomic_store(p, v, __ATOMIC_RELAXED, __HIP_MEMORY_SCOPE_AGENT);
}
__device__ __forceinline__ void cst32(u32t* p, u32t v){
  __hip_atomic_store(p, v, __ATOMIC_RELAXED, __HIP_MEMORY_SCOPE_AGENT);
}

// ---- LDS A-tile, XOR-swizzled 16B chunks (conflict-free ds_read_b128) ----
// u64 slot u (row m): chunk c=u>>1, phys=(c&~7)|((c^m)&7)
__device__ __forceinline__ void aput(u16t* As, int rowu16, int m, int u, u64t v){
  int c = u >> 1;
  int slot = ((c & ~7) | ((c ^ m) & 7))*2 + (u & 1);
  *(u64t*)(As + m*rowu16 + slot*4) = v;
}
__device__ __forceinline__ short8 afrag(const u16t* As, int rowu16, int m, int kb, int q4){
  int c = kb*4 + q4;
  int phys = (c & ~7) | ((c ^ m) & 7);
  return *(const short8*)(As + m*rowu16 + phys*8);
}

// ---- grid barrier: NO cache invalidation. relaxed agent atomics only. ----
__device__ __forceinline__ void gsync(u32t* flags, u32t* gen, u32t e){
  asm volatile("s_waitcnt vmcnt(0) lgkmcnt(0)" ::: "memory");
  __syncthreads();
  if (blockIdx.x == 0){
    if (threadIdx.x > 0 && threadIdx.x < NBLK){
      while (__hip_atomic_load(flags + threadIdx.x*32, __ATOMIC_RELAXED, __HIP_MEMORY_SCOPE_AGENT) < e) ;
    }
    __syncthreads();
    if (threadIdx.x == 0)
      __hip_atomic_store(gen, e, __ATOMIC_RELAXED, __HIP_MEMORY_SCOPE_AGENT);
  } else {
    if (threadIdx.x == 0){
      __hip_atomic_store(flags + blockIdx.x*32, e, __ATOMIC_RELAXED, __HIP_MEMORY_SCOPE_AGENT);
      while (__hip_atomic_load(gen, __ATOMIC_RELAXED, __HIP_MEMORY_SCOPE_AGENT) < e) ;
    }
  }
  __builtin_amdgcn_fence(__ATOMIC_ACQUIRE, "workgroup");
  __syncthreads();
}

__launch_bounds__(NTHR, 1)
__global__ void sqac_kernel(Params p){
  extern __shared__ u16t As[];           // 96KB dynamic A-tile
  __shared__ u16t qkvs[64*192];          // 48KB static qkv exchange
  const int tid0 = threadIdx.x;
  const int blk  = blockIdx.x;
  const int tid  = blk*NTHR + tid0;
  const int lane = tid0 & 63;
  const int wv   = tid0 >> 6;            // wave in block
  const int c16  = lane & 15, q4 = lane >> 4;
  u32t e = 0;

  // ================= P0 stage 1: conversions / swizzles / base =================
  {
    // hB = bf16(h0); cbuf = c0
    for (int idx = tid; idx < 12288; idx += GRIDTH){
      f4 h = *(const f4*)(p.h0 + idx*4);
      *(u64t*)(p.hB + idx*4) = pack4f(h.x, h.y, h.z, h.w);
      *(f4*)(p.cbuf + idx*4) = *(const f4*)(p.c0 + idx*4);
    }
    // Wqkv_s: [h][kb][ntl][lane][8]
    for (int idx = tid; idx < 221184; idx += GRIDTH){
      int l = idx & 63, g2 = idx >> 6;
      int ntl = g2 % 12, kb = (g2/12) % 24, h = g2/288;
      int k0 = kb*32 + ((l>>4)<<3);
      int nl = ntl*16 + (l&15);
      const float* s; int col;
      if (nl < 64){ s = p.Wq; col = h*64 + nl; }
      else if (nl < 128){ s = p.Wk; col = h*64 + nl - 64; }
      else { s = p.Wv; col = h*64 + nl - 128; }
      union { u16t a[8]; short8 v; } t8;
      #pragma unroll
      for (int j = 0; j < 8; j++) t8.a[j] = f2b(s[(size_t)(k0+j)*768 + col]);
      *(short8*)(p.Wqkv_s + (size_t)idx*8) = t8.v;
    }
    // Whhih_s = swizzle(vstack(Whh,Wih)) K=1536 N=3072
    for (int idx = tid; idx < 589824; idx += GRIDTH){
      int l = idx & 63, g2 = idx >> 6;
      int nb = g2 % 192, kb2 = g2 / 192;
      int n  = nb*16 + (l&15);
      int kl = (kb2 % 24)*32 + ((l>>4)<<3);
      const float* s = (kb2 < 24) ? p.Whh : p.Wih;
      union { u16t a[8]; short8 v; } t8;
      #pragma unroll
      for (int j = 0; j < 8; j++) t8.a[j] = f2b(s[(size_t)(kl+j)*3072 + n]);
      *(short8*)(p.Whhih_s + (size_t)idx*8) = t8.v;
    }
    // Wfuse_s swizzle K=1536 N=768
    for (int idx = tid; idx < 147456; idx += GRIDTH){
      int l = idx & 63, g2 = idx >> 6;
      int nb = g2 % 48, kb = g2 / 48;
      int n  = nb*16 + (l&15);
      int k0 = kb*32 + ((l>>4)<<3);
      union { u16t a[8]; short8 v; } t8;
      #pragma unroll
      for (int j = 0; j < 8; j++) t8.a[j] = f2b(p.Wfuse[(size_t)(k0+j)*768 + n]);
      *(short8*)(p.Wfuse_s + (size_t)idx*8) = t8.v;
    }
    // Wfuse_bf row-major bf16
    for (int idx = tid; idx < 294912; idx += GRIDTH){
      f4 v = *(const f4*)(p.Wfuse + idx*4);
      *(u64t*)(p.Wfuse_bf + idx*4) = pack4f(v.x, v.y, v.z, v.w);
    }
    // base = q@Wqh + a@Wah + (bqh+bah+bih+bhh)
    for (int w = tid; w < 24576; w += GRIDTH){
      int bg = w / 3072, n = w - bg*3072;
      float acc[8];
      #pragma unroll
      for (int bi = 0; bi < 8; bi++) acc[bi] = 0.f;
      for (int k = 0; k < 768; k++){
        float wq = p.Wqh[(size_t)k*3072 + n];
        float wa = p.Wah[(size_t)k*3072 + n];
        #pragma unroll
        for (int bi = 0; bi < 8; bi++){
          int b = bg*8 + bi;
          acc[bi] += p.question[b*768 + k]*wq + p.answer[b*768 + k]*wa;
        }
      }
      float bias = p.bqh[n] + p.bah[n] + p.bih[n] + p.bhh[n];
      #pragma unroll
      for (int bi = 0; bi < 8; bi++)
        p.base[(size_t)(bg*8+bi)*3072 + n] = acc[bi] + bias;
    }
    // bfW = bfuse @ Wih
    for (int n = tid; n < 3072; n += GRIDTH){
      float a = 0.f;
      for (int k = 0; k < 768; k++) a += p.bfuse[k]*p.Wih[(size_t)k*3072 + n];
      p.bfW[n] = a;
    }
  }
  __threadfence();   // one-time flush so normal-stored setup data reaches LLC
  e++; gsync(p.flags, p.gen, e);

  // ================= P0 stage 2: Wcomb = Wfuse @ Wih (MFMA) =================
  {
    int w = tid >> 6;                 // 0..287
    int mt = w % 96, ntg = w / 96;    // ntg 0..2 (x64 nt)
    for (int nt = ntg*64; nt < ntg*64 + 64; nt++){
      f4 acc = {0.f,0.f,0.f,0.f};
      for (int kb = 0; kb < 24; kb++){
        short8 af = *(const short8*)(p.Wfuse_bf + (size_t)(mt*16 + c16)*768 + kb*32 + q4*8);
        short8 bf = *(const short8*)(p.Whhih_s + ((size_t)((24+kb)*192 + nt))*512 + lane*8);
        acc = mfma16(af, bf, acc);
      }
      #pragma unroll
      for (int r = 0; r < 4; r++){
        int k1 = mt*16 + q4*4 + r;
        p.Wcomb_s[((size_t)((k1>>5)*192 + nt))*512 + (size_t)((((k1>>3)&3)*16 + c16)*8 + (k1&7))] = f2b(acc[r]);
      }
    }
  }
  __threadfence();
  e++; gsync(p.flags, p.gen, e);

  // ================= main scan: 2 barriers per step =================
  for (int t = 0; t < T_; t++){

    // ---------- PA ----------
    if (blk < 24){
      // QKV GEMM + 2-token attention for head h, b-half bh
      const int h = blk >> 1, bh = blk & 1;
      {
        int m = tid0 >> 2, j = tid0 & 3;      // 64 rows, 4 threads/row
        int b = bh*32 + (m & 31);
        int st;
        if (m < 32){ int pt = p.ping[b*T_ + t]; st = pt - 1; if (st < 0) st = 0; if (st > T_-1) st = T_-1; }
        else st = t;
        const float* src = p.x + ((size_t)(st*64 + b))*768;
        for (int i = 0; i < 48; i++){
          int u = j + 4*i;                    // 192 u64/row (768 bf16)
          u64t s0 = cld64(src + u*4), s1 = cld64(src + u*4 + 2);
          aput(As, 768, m, u, pack4u(s0, s1));
        }
      }
      __syncthreads();
      f4 acc[3][4];
      #pragma unroll
      for (int i = 0; i < 3; i++)
        #pragma unroll
        for (int mt = 0; mt < 4; mt++) acc[i][mt] = f4{0.f,0.f,0.f,0.f};
      for (int kb = 0; kb < 24; kb++){
        short8 af[4];
        #pragma unroll
        for (int mt = 0; mt < 4; mt++) af[mt] = afrag(As, 768, mt*16 + c16, kb, q4);
        #pragma unroll
        for (int i = 0; i < 3; i++){
          short8 bf = *(const short8*)(p.Wqkv_s + ((size_t)((h*24 + kb)*12 + wv*3 + i))*512 + lane*8);
          #pragma unroll
          for (int mt = 0; mt < 4; mt++) acc[i][mt] = mfma16(af[mt], bf, acc[i][mt]);
        }
      }
      #pragma unroll
      for (int i = 0; i < 3; i++){
        int nl = (wv*3 + i)*16 + c16;
        float bias = (nl < 64) ? p.bq[h*64+nl] : (nl < 128 ? p.bk[h*64+nl-64] : p.bv[h*64+nl-128]);
        #pragma unroll
        for (int mt = 0; mt < 4; mt++)
          #pragma unroll
          for (int r = 0; r < 4; r++)
            qkvs[(mt*16 + q4*4 + r)*192 + nl] = f2b(acc[i][mt][r] + bias);
      }
      __syncthreads();
      for (int pi = 0; pi < 8; pi++){
        int bi = wv*8 + pi;
        const u16t* L = qkvs + bi*192;
        const u16t* R = qkvs + (32+bi)*192;
        float ql = b2f(L[lane]), kl = b2f(L[64+lane]), vl = b2f(L[128+lane]);
        float qr = b2f(R[lane]), kr = b2f(R[64+lane]), vr = b2f(R[128+lane]);
        float sll = wsum(ql*kl)*0.125f, slr = wsum(ql*kr)*0.125f;
        float srl = wsum(qr*kl)*0.125f, srr = wsum(qr*kr)*0.125f;
        float ml = fmaxf(sll, slr), mr = fmaxf(srl, srr);
        float ell = __expf(sll-ml), elr = __expf(slr-ml);
        float erl = __expf(srl-mr), err = __expf(srr-mr);
        float il = 1.0f/(ell+elr), ir = 1.0f/(erl+err);
        float cl = (ell*il)*vl + (elr*il)*vr;
        float cr = (erl*ir)*vl + (err*ir)*vr;
        float cl2 = __shfl_xor(cl, 1), cr2 = __shfl_xor(cr, 1);
        if (!(lane & 1)){
          int b = bh*32 + bi;
          cst32((u32t*)(p.ctxb + (size_t)b*1536 + h*64 + lane),
                (u32t)f2b(cl) | ((u32t)f2b(cl2) << 16));
          cst32((u32t*)(p.ctxb + (size_t)b*1536 + 768 + h*64 + lane),
                (u32t)f2b(cr) | ((u32t)f2b(cr2) << 16));
        }
      }
    } else {
      // gatesHX = [h | masked_x] @ vstack(Whh, Wih)   (K=1536)
      const int local = blk - 24, mh = local & 1, ng = local >> 1;  // ng 0..23
      const int b0 = mh*32;
      {
        int m = tid0 >> 3, j = tid0 & 7;     // 32 rows, 8 threads/row
        int b = b0 + m;
        int pt = p.ping[b*T_ + t];
        bool cond = (pt > 0) && (t > 0);
        const u64t* hsrc = (const u64t*)(p.hB + (size_t)b*768);
        for (int i = 0; i < 24; i++){
          int u = j + 8*i;                   // h-part u64 0..191
          aput(As, 1536, m, u, cld64(hsrc + u));
        }
        const float* xsrc = p.x + ((size_t)(t*64 + b))*768;
        for (int i = 0; i < 24; i++){
          int u = j + 8*i;                   // x-part u64 192..383
          u64t v = 0;
          if (!cond){
            u64t s0 = cld64(xsrc + u*4), s1 = cld64(xsrc + u*4 + 2);
            v = pack4u(s0, s1);
          }
          aput(As, 1536, m, 192 + u, v);
        }
      }
      __syncthreads();
      f4 acc[2][2];
      #pragma unroll
      for (int i = 0; i < 2; i++)
        #pragma unroll
        for (int mt = 0; mt < 2; mt++) acc[i][mt] = f4{0.f,0.f,0.f,0.f};
      for (int kb = 0; kb < 48; kb++){
        short8 af[2];
        #pragma unroll
        for (int mt = 0; mt < 2; mt++) af[mt] = afrag(As, 1536, mt*16 + c16, kb, q4);
        #pragma unroll
        for (int i = 0; i < 2; i++){
          int nt = ng*8 + wv*2 + i;
          short8 bf = *(const short8*)(p.Whhih_s + ((size_t)(kb*192 + nt))*512 + lane*8);
          #pragma unroll
          for (int mt = 0; mt < 2; mt++) acc[i][mt] = mfma16(af[mt], bf, acc[i][mt]);
        }
      }
      #pragma unroll
      for (int i = 0; i < 2; i++){
        int n = (ng*8 + wv*2 + i)*16 + c16;
        #pragma unroll
        for (int mt = 0; mt < 2; mt++)
          #pragma unroll
          for (int r = 0; r < 4; r++){
            int b = b0 + mt*16 + q4*4 + r;
            cstf(p.gatesHX + (size_t)b*3072 + n, acc[i][mt][r]);
          }
      }
    }
    e++; gsync(p.flags, p.gen, e);

    // ---------- PB ----------
    if (blk < 48){
      // gates = base + gatesHX + cond*(ctx@Wcomb + bfW); LSTM pointwise
      const int mh = blk & 1, jjg = blk >> 1;   // jjg 0..23
      const int b0 = mh*32;
      {
        int m = tid0 >> 3, j = tid0 & 7;
        const u64t* src = (const u64t*)(p.ctxb + (size_t)(b0+m)*1536);
        for (int i = 0; i < 48; i++){
          int u = j + 8*i;                   // 384 u64/row (1536 bf16)
          aput(As, 1536, m, u, cld64(src + u));
        }
      }
      __syncthreads();
      const int jjt = jjg*2 + (wv & 1), mt = wv >> 1;
      f4 acc[4];
      #pragma unroll
      for (int g = 0; g < 4; g++) acc[g] = f4{0.f,0.f,0.f,0.f};
      for (int kb = 0; kb < 48; kb++){
        short8 af = afrag(As, 1536, mt*16 + c16, kb, q4);
        #pragma unroll
        for (int g = 0; g < 4; g++){
          short8 bf = *(const short8*)(p.Wcomb_s + ((size_t)(kb*192 + g*48 + jjt))*512 + lane*8);
          acc[g] = mfma16(af, bf, acc[g]);
        }
      }
      const int jj = jjt*16 + c16;
      float bfw[4];
      #pragma unroll
      for (int g = 0; g < 4; g++) bfw[g] = p.bfW[g*768 + jj];
      #pragma unroll
      for (int r = 0; r < 4; r++){
        int b = b0 + mt*16 + q4*4 + r;
        int pt = p.ping[b*T_ + t];
        bool cond = (pt > 0) && (t > 0);
        size_t g0 = (size_t)b*3072 + jj;
        float gi = p.base[g0]      + cldf(p.gatesHX + g0);
        float gf = p.base[g0+768]  + cldf(p.gatesHX + g0+768);
        float gg = p.base[g0+1536] + cldf(p.gatesHX + g0+1536);
        float go = p.base[g0+2304] + cldf(p.gatesHX + g0+2304);
        if (cond){
          gi += acc[0][r] + bfw[0]; gf += acc[1][r] + bfw[1];
          gg += acc[2][r] + bfw[2]; go += acc[3][r] + bfw[3];
        }
        float co = p.cbuf[b*768 + jj];
        float cn = sigm(gf)*co + sigm(gi)*tanh_(gg);
        float hh = sigm(go)*tanh_(cn);
        p.out[((size_t)(t*64 + b))*768 + jj] = hh;
        p.cbuf[b*768 + jj] = cn;
        float hp = __shfl_xor(hh, 1);
        if (!(c16 & 1))
          cst32((u32t*)(p.hB + (size_t)b*768 + jj), (u32t)f2b(hh) | ((u32t)f2b(hp) << 16));
        if (t == T_-1){
          p.out[HALL + b*768 + jj] = hh;
          p.out[HALL + 49152 + b*768 + jj] = cn;
        }
      }
    } else {
      // fused = ctx@Wfuse + bfuse; write x[t] for cond rows (future left-gathers)
      const int local = blk - 48, mh = local & 1, ng = local >> 1;  // ng 0..11
      const int b0 = mh*32;
      {
        int m = tid0 >> 3, j = tid0 & 7;
        const u64t* src = (const u64t*)(p.ctxb + (size_t)(b0+m)*1536);
        for (int i = 0; i < 48; i++){
          int u = j + 8*i;
          aput(As, 1536, m, u, cld64(src + u));
        }
      }
      __syncthreads();
      const int nt = ng*4 + wv;
      f4 acc[2];
      #pragma unroll
      for (int mt = 0; mt < 2; mt++) acc[mt] = f4{0.f,0.f,0.f,0.f};
      for (int kb = 0; kb < 48; kb++){
        short8 bf = *(const short8*)(p.Wfuse_s + ((size_t)(kb*48 + nt))*512 + lane*8);
        #pragma unroll
        for (int mt = 0; mt < 2; mt++){
          short8 af = afrag(As, 1536, mt*16 + c16, kb, q4);
          acc[mt] = mfma16(af, bf, acc[mt]);
        }
      }
      const int n = nt*16 + c16;
      const float bias = p.bfuse[n];
      #pragma unroll
      for (int mt = 0; mt < 2; mt++)
        #pragma unroll
        for (int r = 0; r < 4; r++){
          int b = b0 + mt*16 + q4*4 + r;
          int pt = p.ping[b*T_ + t];
          if (pt > 0 && t > 0)
            cstf(p.x + ((size_t)(t*64 + b))*768 + n, acc[mt][r] + bias);
        }
    }
    e++; gsync(p.flags, p.gen, e);
  }
}

extern "C" void kernel_launch(void* const* d_in, const int* in_sizes, int n_in,
                              void* d_out, int out_size, void* d_ws, size_t ws_size,
                              hipStream_t stream)
{
  (void)in_sizes; (void)n_in; (void)out_size; (void)ws_size;
  char* ws = (char*)d_ws;
  size_t off = 0;
  auto take = [&](size_t bytes)->void*{
    void* ptr = ws + off;
    off += (bytes + 255) & ~(size_t)255;
    return ptr;
  };

  Params p;
  p.question = (const float*)d_in[0];
  p.answer   = (const float*)d_in[1];
  p.x        = (float*)d_in[2];
  p.ping     = (const int*)d_in[3];
  p.h0  = (const float*)d_in[4];  p.c0  = (const float*)d_in[5];
  p.Wqh = (const float*)d_in[6];  p.bqh = (const float*)d_in[7];
  p.Wah = (const float*)d_in[8];  p.bah = (const float*)d_in[9];
  p.Wih = (const float*)d_in[10]; p.bih = (const float*)d_in[11];
  p.Whh = (const float*)d_in[12]; p.bhh = (const float*)d_in[13];
  p.Wq  = (const float*)d_in[14]; p.bq  = (const float*)d_in[15];
  p.Wk  = (const float*)d_in[16]; p.bk  = (const float*)d_in[17];
  p.Wv  = (const float*)d_in[18]; p.bv  = (const float*)d_in[19];
  p.Wfuse = (const float*)d_in[20]; p.bfuse = (const float*)d_in[21];
  p.out = (float*)d_out;

  u32t* sync = (u32t*)take(16384);
  p.flags = sync;                 // blk*32 stride (128B lines)
  p.gen   = sync + 3072;

  p.Wqkv_s   = (u16t*)take((size_t)221184*16);   // 3.54 MB
  p.Whhih_s  = (u16t*)take((size_t)589824*16);   // 9.44 MB
  p.Wfuse_s  = (u16t*)take((size_t)147456*16);   // 2.36 MB
  p.Wcomb_s  = (u16t*)take((size_t)589824*16);   // 9.44 MB
  p.Wfuse_bf = (u16t*)take((size_t)1536*768*2);  // 2.36 MB
  p.base     = (float*)take((size_t)64*3072*4);
  p.gatesHX  = (float*)take((size_t)64*3072*4);
  p.ctxb     = (u16t*)take((size_t)64*1536*2);
  p.hB       = (u16t*)take((size_t)64*768*2);
  p.cbuf     = (float*)take((size_t)64*768*4);
  p.bfW      = (float*)take((size_t)3072*4);

  hipFuncSetAttribute(reinterpret_cast<const void*>(sqac_kernel),
                      hipFuncAttributeMaxDynamicSharedMemorySize, 98304);
  hipMemsetAsync(sync, 0, 16384, stream);
  hipLaunchKernelGGL(sqac_kernel, dim3(NBLK), dim3(NTHR), 98304, stream, p);
}

// Round 4
// 27352.585 us; speedup vs baseline: 3.1234x; 1.0312x over previous
//
#include <hip/hip_runtime.h>
#include <cstdint>
#include <cstddef>

// SQACILSTM round 4: identical structure to round 3 (72 persistent blocks,
// 2 fence-free grid barriers per step, LLC-coherent cross-block data).
// Change: all bulk coherent LOADS are hand-batched inline asm
// (8x global_load_* sc0 sc1 + one s_waitcnt) instead of per-element
// __hip_atomic_load, which serialized at one LLC round-trip per element
// (round-3 counters: MfmaUtil 0.66%, VALUBusy 1.4%, 108us/step = latency).

#define T_   256
#define B_   64
#define NBLK 72
#define NTHR 256
#define GRIDTH (NBLK*NTHR)
#define HALL 12582912   // 256*64*768

typedef __attribute__((ext_vector_type(8))) short short8;
typedef __attribute__((ext_vector_type(4))) float f4;
typedef unsigned long long u64t;
typedef unsigned short u16t;
typedef unsigned int u32t;

struct Params {
  const float* question; const float* answer; float* x; const int* ping;
  const float* h0; const float* c0;
  const float* Wqh; const float* bqh; const float* Wah; const float* bah;
  const float* Wih; const float* bih; const float* Whh; const float* bhh;
  const float* Wq;  const float* bq;  const float* Wk;  const float* bk;
  const float* Wv;  const float* bv;  const float* Wfuse; const float* bfuse;
  float* out;
  u32t* flags; u32t* gen;
  u16t* Wqkv_s; u16t* Whhih_s; u16t* Wfuse_s; u16t* Wcomb_s; u16t* Wfuse_bf;
  float* base; float* gatesHX; u16t* ctxb; u16t* hB; float* cbuf; float* bfW;
};

__device__ __forceinline__ u16t f2b(float f){
  union { float f; u32t u; } a; a.f = f;
  u32t u = a.u;
  u32t r = u + 0x7FFFu + ((u >> 16) & 1u);
  return (u16t)(r >> 16);
}
__device__ __forceinline__ float b2f(u16t u){
  union { u32t u; float f; } a; a.u = ((u32t)u) << 16; return a.f;
}
__device__ __forceinline__ u64t pack4f(float a, float b, float c, float d){
  return (u64t)f2b(a) | ((u64t)f2b(b)<<16) | ((u64t)f2b(c)<<32) | ((u64t)f2b(d)<<48);
}
__device__ __forceinline__ float sigm(float x){ return 1.0f/(1.0f+__expf(-x)); }
__device__ __forceinline__ float tanh_(float x){ return 2.0f/(1.0f+__expf(-2.0f*x)) - 1.0f; }
__device__ __forceinline__ f4 mfma16(short8 a, short8 b, f4 c){
  return __builtin_amdgcn_mfma_f32_16x16x32_bf16(a, b, c, 0, 0, 0);
}
__device__ __forceinline__ float wsum(float x){
  #pragma unroll
  for (int off = 32; off > 0; off >>= 1) x += __shfl_xor(x, off, 64);
  return x;
}

// ---- batched coherent loads (LLC / sc0 sc1), one waitcnt per 8 ----
__device__ __forceinline__ void cldx4_8(f4&d0,f4&d1,f4&d2,f4&d3,f4&d4,f4&d5,f4&d6,f4&d7,
  const float*a0,const float*a1,const float*a2,const float*a3,
  const float*a4,const float*a5,const float*a6,const float*a7){
  asm volatile(
    "global_load_dwordx4 %0, %8, off sc0 sc1\n\t"
    "global_load_dwordx4 %1, %9, off sc0 sc1\n\t"
    "global_load_dwordx4 %2, %10, off sc0 sc1\n\t"
    "global_load_dwordx4 %3, %11, off sc0 sc1\n\t"
    "global_load_dwordx4 %4, %12, off sc0 sc1\n\t"
    "global_load_dwordx4 %5, %13, off sc0 sc1\n\t"
    "global_load_dwordx4 %6, %14, off sc0 sc1\n\t"
    "global_load_dwordx4 %7, %15, off sc0 sc1\n\t"
    "s_waitcnt vmcnt(0)"
    : "=&v"(d0),"=&v"(d1),"=&v"(d2),"=&v"(d3),"=&v"(d4),"=&v"(d5),"=&v"(d6),"=&v"(d7)
    : "v"(a0),"v"(a1),"v"(a2),"v"(a3),"v"(a4),"v"(a5),"v"(a6),"v"(a7));
}
__device__ __forceinline__ void cldx2_8(u64t&d0,u64t&d1,u64t&d2,u64t&d3,u64t&d4,u64t&d5,u64t&d6,u64t&d7,
  const void*a0,const void*a1,const void*a2,const void*a3,
  const void*a4,const void*a5,const void*a6,const void*a7){
  asm volatile(
    "global_load_dwordx2 %0, %8, off sc0 sc1\n\t"
    "global_load_dwordx2 %1, %9, off sc0 sc1\n\t"
    "global_load_dwordx2 %2, %10, off sc0 sc1\n\t"
    "global_load_dwordx2 %3, %11, off sc0 sc1\n\t"
    "global_load_dwordx2 %4, %12, off sc0 sc1\n\t"
    "global_load_dwordx2 %5, %13, off sc0 sc1\n\t"
    "global_load_dwordx2 %6, %14, off sc0 sc1\n\t"
    "global_load_dwordx2 %7, %15, off sc0 sc1\n\t"
    "s_waitcnt vmcnt(0)"
    : "=&v"(d0),"=&v"(d1),"=&v"(d2),"=&v"(d3),"=&v"(d4),"=&v"(d5),"=&v"(d6),"=&v"(d7)
    : "v"(a0),"v"(a1),"v"(a2),"v"(a3),"v"(a4),"v"(a5),"v"(a6),"v"(a7));
}
__device__ __forceinline__ void cldd8(float&d0,float&d1,float&d2,float&d3,float&d4,float&d5,float&d6,float&d7,
  const float*a0,const float*a1,const float*a2,const float*a3,
  const float*a4,const float*a5,const float*a6,const float*a7){
  asm volatile(
    "global_load_dword %0, %8, off sc0 sc1\n\t"
    "global_load_dword %1, %9, off sc0 sc1\n\t"
    "global_load_dword %2, %10, off sc0 sc1\n\t"
    "global_load_dword %3, %11, off sc0 sc1\n\t"
    "global_load_dword %4, %12, off sc0 sc1\n\t"
    "global_load_dword %5, %13, off sc0 sc1\n\t"
    "global_load_dword %6, %14, off sc0 sc1\n\t"
    "global_load_dword %7, %15, off sc0 sc1\n\t"
    "s_waitcnt vmcnt(0)"
    : "=&v"(d0),"=&v"(d1),"=&v"(d2),"=&v"(d3),"=&v"(d4),"=&v"(d5),"=&v"(d6),"=&v"(d7)
    : "v"(a0),"v"(a1),"v"(a2),"v"(a3),"v"(a4),"v"(a5),"v"(a6),"v"(a7));
}

// ---- coherent stores (fire-and-forget; drained by barrier's vmcnt wait) ----
__device__ __forceinline__ void cstf(float* p, float v){
  __hip_atomic_store(p, v, __ATOMIC_RELAXED, __HIP_MEMORY_SCOPE_AGENT);
}
__device__ __forceinline__ void cst32(u32t* p, u32t v){
  __hip_atomic_store(p, v, __ATOMIC_RELAXED, __HIP_MEMORY_SCOPE_AGENT);
}

// ---- LDS A-tile, XOR-swizzled 16B chunks ----
__device__ __forceinline__ void aput(u16t* As, int rowu16, int m, int u, u64t v){
  int c = u >> 1;
  int slot = ((c & ~7) | ((c ^ m) & 7))*2 + (u & 1);
  *(u64t*)(As + m*rowu16 + slot*4) = v;
}
__device__ __forceinline__ short8 afrag(const u16t* As, int rowu16, int m, int kb, int q4){
  int c = kb*4 + q4;
  int phys = (c & ~7) | ((c ^ m) & 7);
  return *(const short8*)(As + m*rowu16 + phys*8);
}

// ---- grid barrier: relaxed agent atomics only, no cache invalidation ----
__device__ __forceinline__ void gsync(u32t* flags, u32t* gen, u32t e){
  asm volatile("s_waitcnt vmcnt(0) lgkmcnt(0)" ::: "memory");
  __syncthreads();
  if (blockIdx.x == 0){
    if (threadIdx.x > 0 && threadIdx.x < NBLK){
      while (__hip_atomic_load(flags + threadIdx.x*32, __ATOMIC_RELAXED, __HIP_MEMORY_SCOPE_AGENT) < e) ;
    }
    __syncthreads();
    if (threadIdx.x == 0)
      __hip_atomic_store(gen, e, __ATOMIC_RELAXED, __HIP_MEMORY_SCOPE_AGENT);
  } else {
    if (threadIdx.x == 0){
      __hip_atomic_store(flags + blockIdx.x*32, e, __ATOMIC_RELAXED, __HIP_MEMORY_SCOPE_AGENT);
      while (__hip_atomic_load(gen, __ATOMIC_RELAXED, __HIP_MEMORY_SCOPE_AGENT) < e) ;
    }
  }
  __builtin_amdgcn_fence(__ATOMIC_ACQUIRE, "workgroup");
  __syncthreads();
}

__launch_bounds__(NTHR, 1)
__global__ void sqac_kernel(Params p){
  extern __shared__ u16t As[];           // 96KB dynamic A-tile
  __shared__ u16t qkvs[64*192];          // 24KB qkv exchange
  const int tid0 = threadIdx.x;
  const int blk  = blockIdx.x;
  const int tid  = blk*NTHR + tid0;
  const int lane = tid0 & 63;
  const int wv   = tid0 >> 6;
  const int c16  = lane & 15, q4 = lane >> 4;
  u32t e = 0;

  // ================= P0 stage 1: conversions / swizzles / base =================
  {
    for (int idx = tid; idx < 12288; idx += GRIDTH){
      f4 h = *(const f4*)(p.h0 + idx*4);
      *(u64t*)(p.hB + idx*4) = pack4f(h.x, h.y, h.z, h.w);
      *(f4*)(p.cbuf + idx*4) = *(const f4*)(p.c0 + idx*4);
    }
    for (int idx = tid; idx < 221184; idx += GRIDTH){
      int l = idx & 63, g2 = idx >> 6;
      int ntl = g2 % 12, kb = (g2/12) % 24, h = g2/288;
      int k0 = kb*32 + ((l>>4)<<3);
      int nl = ntl*16 + (l&15);
      const float* s; int col;
      if (nl < 64){ s = p.Wq; col = h*64 + nl; }
      else if (nl < 128){ s = p.Wk; col = h*64 + nl - 64; }
      else { s = p.Wv; col = h*64 + nl - 128; }
      union { u16t a[8]; short8 v; } t8;
      #pragma unroll
      for (int j = 0; j < 8; j++) t8.a[j] = f2b(s[(size_t)(k0+j)*768 + col]);
      *(short8*)(p.Wqkv_s + (size_t)idx*8) = t8.v;
    }
    for (int idx = tid; idx < 589824; idx += GRIDTH){
      int l = idx & 63, g2 = idx >> 6;
      int nb = g2 % 192, kb2 = g2 / 192;
      int n  = nb*16 + (l&15);
      int kl = (kb2 % 24)*32 + ((l>>4)<<3);
      const float* s = (kb2 < 24) ? p.Whh : p.Wih;
      union { u16t a[8]; short8 v; } t8;
      #pragma unroll
      for (int j = 0; j < 8; j++) t8.a[j] = f2b(s[(size_t)(kl+j)*3072 + n]);
      *(short8*)(p.Whhih_s + (size_t)idx*8) = t8.v;
    }
    for (int idx = tid; idx < 147456; idx += GRIDTH){
      int l = idx & 63, g2 = idx >> 6;
      int nb = g2 % 48, kb = g2 / 48;
      int n  = nb*16 + (l&15);
      int k0 = kb*32 + ((l>>4)<<3);
      union { u16t a[8]; short8 v; } t8;
      #pragma unroll
      for (int j = 0; j < 8; j++) t8.a[j] = f2b(p.Wfuse[(size_t)(k0+j)*768 + n]);
      *(short8*)(p.Wfuse_s + (size_t)idx*8) = t8.v;
    }
    for (int idx = tid; idx < 294912; idx += GRIDTH){
      f4 v = *(const f4*)(p.Wfuse + idx*4);
      *(u64t*)(p.Wfuse_bf + idx*4) = pack4f(v.x, v.y, v.z, v.w);
    }
    for (int w = tid; w < 24576; w += GRIDTH){
      int bg = w / 3072, n = w - bg*3072;
      float acc[8];
      #pragma unroll
      for (int bi = 0; bi < 8; bi++) acc[bi] = 0.f;
      for (int k = 0; k < 768; k++){
        float wq = p.Wqh[(size_t)k*3072 + n];
        float wa = p.Wah[(size_t)k*3072 + n];
        #pragma unroll
        for (int bi = 0; bi < 8; bi++){
          int b = bg*8 + bi;
          acc[bi] += p.question[b*768 + k]*wq + p.answer[b*768 + k]*wa;
        }
      }
      float bias = p.bqh[n] + p.bah[n] + p.bih[n] + p.bhh[n];
      #pragma unroll
      for (int bi = 0; bi < 8; bi++)
        p.base[(size_t)(bg*8+bi)*3072 + n] = acc[bi] + bias;
    }
    for (int n = tid; n < 3072; n += GRIDTH){
      float a = 0.f;
      for (int k = 0; k < 768; k++) a += p.bfuse[k]*p.Wih[(size_t)k*3072 + n];
      p.bfW[n] = a;
    }
  }
  __threadfence();
  e++; gsync(p.flags, p.gen, e);

  // ================= P0 stage 2: Wcomb = Wfuse @ Wih (MFMA) =================
  {
    int w = tid >> 6;
    int mt = w % 96, ntg = w / 96;
    for (int nt = ntg*64; nt < ntg*64 + 64; nt++){
      f4 acc = {0.f,0.f,0.f,0.f};
      for (int kb = 0; kb < 24; kb++){
        short8 af = *(const short8*)(p.Wfuse_bf + (size_t)(mt*16 + c16)*768 + kb*32 + q4*8);
        short8 bf = *(const short8*)(p.Whhih_s + ((size_t)((24+kb)*192 + nt))*512 + lane*8);
        acc = mfma16(af, bf, acc);
      }
      #pragma unroll
      for (int r = 0; r < 4; r++){
        int k1 = mt*16 + q4*4 + r;
        p.Wcomb_s[((size_t)((k1>>5)*192 + nt))*512 + (size_t)((((k1>>3)&3)*16 + c16)*8 + (k1&7))] = f2b(acc[r]);
      }
    }
  }
  __threadfence();
  e++; gsync(p.flags, p.gen, e);

  // ================= main scan: 2 barriers per step =================
  for (int t = 0; t < T_; t++){

    // ---------- PA ----------
    if (blk < 24){
      const int h = blk >> 1, bh = blk & 1;
      {
        int m = tid0 >> 2, j = tid0 & 3;      // 64 rows, 4 threads/row
        int b = bh*32 + (m & 31);
        int st;
        if (m < 32){ int pt = p.ping[b*T_ + t]; st = pt - 1; if (st < 0) st = 0; if (st > T_-1) st = T_-1; }
        else st = t;
        const float* src = p.x + ((size_t)(st*64 + b))*768;
        #pragma unroll
        for (int g = 0; g < 6; g++){
          f4 d0,d1,d2,d3,d4,d5,d6,d7;
          int u0 = j + 4*(g*8);
          cldx4_8(d0,d1,d2,d3,d4,d5,d6,d7,
                  src+(u0    )*4, src+(u0+ 4)*4, src+(u0+ 8)*4, src+(u0+12)*4,
                  src+(u0+16)*4, src+(u0+20)*4, src+(u0+24)*4, src+(u0+28)*4);
          aput(As,768,m,u0,    pack4f(d0.x,d0.y,d0.z,d0.w));
          aput(As,768,m,u0+ 4, pack4f(d1.x,d1.y,d1.z,d1.w));
          aput(As,768,m,u0+ 8, pack4f(d2.x,d2.y,d2.z,d2.w));
          aput(As,768,m,u0+12, pack4f(d3.x,d3.y,d3.z,d3.w));
          aput(As,768,m,u0+16, pack4f(d4.x,d4.y,d4.z,d4.w));
          aput(As,768,m,u0+20, pack4f(d5.x,d5.y,d5.z,d5.w));
          aput(As,768,m,u0+24, pack4f(d6.x,d6.y,d6.z,d6.w));
          aput(As,768,m,u0+28, pack4f(d7.x,d7.y,d7.z,d7.w));
        }
      }
      __syncthreads();
      f4 acc[3][4];
      #pragma unroll
      for (int i = 0; i < 3; i++)
        #pragma unroll
        for (int mt = 0; mt < 4; mt++) acc[i][mt] = f4{0.f,0.f,0.f,0.f};
      for (int kb = 0; kb < 24; kb++){
        short8 af[4];
        #pragma unroll
        for (int mt = 0; mt < 4; mt++) af[mt] = afrag(As, 768, mt*16 + c16, kb, q4);
        #pragma unroll
        for (int i = 0; i < 3; i++){
          short8 bf = *(const short8*)(p.Wqkv_s + ((size_t)((h*24 + kb)*12 + wv*3 + i))*512 + lane*8);
          #pragma unroll
          for (int mt = 0; mt < 4; mt++) acc[i][mt] = mfma16(af[mt], bf, acc[i][mt]);
        }
      }
      #pragma unroll
      for (int i = 0; i < 3; i++){
        int nl = (wv*3 + i)*16 + c16;
        float bias = (nl < 64) ? p.bq[h*64+nl] : (nl < 128 ? p.bk[h*64+nl-64] : p.bv[h*64+nl-128]);
        #pragma unroll
        for (int mt = 0; mt < 4; mt++)
          #pragma unroll
          for (int r = 0; r < 4; r++)
            qkvs[(mt*16 + q4*4 + r)*192 + nl] = f2b(acc[i][mt][r] + bias);
      }
      __syncthreads();
      for (int pi = 0; pi < 8; pi++){
        int bi = wv*8 + pi;
        const u16t* L = qkvs + bi*192;
        const u16t* R = qkvs + (32+bi)*192;
        float ql = b2f(L[lane]), kl = b2f(L[64+lane]), vl = b2f(L[128+lane]);
        float qr = b2f(R[lane]), kr = b2f(R[64+lane]), vr = b2f(R[128+lane]);
        float sll = wsum(ql*kl)*0.125f, slr = wsum(ql*kr)*0.125f;
        float srl = wsum(qr*kl)*0.125f, srr = wsum(qr*kr)*0.125f;
        float ml = fmaxf(sll, slr), mr = fmaxf(srl, srr);
        float ell = __expf(sll-ml), elr = __expf(slr-ml);
        float erl = __expf(srl-mr), err = __expf(srr-mr);
        float il = 1.0f/(ell+elr), ir = 1.0f/(erl+err);
        float cl = (ell*il)*vl + (elr*il)*vr;
        float cr = (erl*ir)*vl + (err*ir)*vr;
        float cl2 = __shfl_xor(cl, 1), cr2 = __shfl_xor(cr, 1);
        if (!(lane & 1)){
          int b = bh*32 + bi;
          cst32((u32t*)(p.ctxb + (size_t)b*1536 + h*64 + lane),
                (u32t)f2b(cl) | ((u32t)f2b(cl2) << 16));
          cst32((u32t*)(p.ctxb + (size_t)b*1536 + 768 + h*64 + lane),
                (u32t)f2b(cr) | ((u32t)f2b(cr2) << 16));
        }
      }
    } else {
      // gatesHX = [h | masked_x] @ vstack(Whh, Wih)
      const int local = blk - 24, mh = local & 1, ng = local >> 1;
      const int b0 = mh*32;
      {
        int m = tid0 >> 3, j = tid0 & 7;     // 32 rows, 8 threads/row
        int b = b0 + m;
        int pt = p.ping[b*T_ + t];
        bool cond = (pt > 0) && (t > 0);
        const u64t* hsrc = (const u64t*)(p.hB + (size_t)b*768);
        #pragma unroll
        for (int g = 0; g < 3; g++){
          u64t d0,d1,d2,d3,d4,d5,d6,d7;
          int u0 = j + 8*(g*8);
          cldx2_8(d0,d1,d2,d3,d4,d5,d6,d7,
                  hsrc+u0, hsrc+u0+8, hsrc+u0+16, hsrc+u0+24,
                  hsrc+u0+32, hsrc+u0+40, hsrc+u0+48, hsrc+u0+56);
          aput(As,1536,m,u0,    d0); aput(As,1536,m,u0+ 8,d1);
          aput(As,1536,m,u0+16, d2); aput(As,1536,m,u0+24,d3);
          aput(As,1536,m,u0+32, d4); aput(As,1536,m,u0+40,d5);
          aput(As,1536,m,u0+48, d6); aput(As,1536,m,u0+56,d7);
        }
        if (cond){
          #pragma unroll
          for (int i = 0; i < 24; i++) aput(As,1536,m,192 + j + 8*i, 0ull);
        } else {
          const float* xsrc = p.x + ((size_t)(t*64 + b))*768;
          #pragma unroll
          for (int g = 0; g < 3; g++){
            f4 d0,d1,d2,d3,d4,d5,d6,d7;
            int u0 = j + 8*(g*8);
            cldx4_8(d0,d1,d2,d3,d4,d5,d6,d7,
                    xsrc+(u0    )*4, xsrc+(u0+ 8)*4, xsrc+(u0+16)*4, xsrc+(u0+24)*4,
                    xsrc+(u0+32)*4, xsrc+(u0+40)*4, xsrc+(u0+48)*4, xsrc+(u0+56)*4);
            aput(As,1536,m,192+u0,    pack4f(d0.x,d0.y,d0.z,d0.w));
            aput(As,1536,m,192+u0+ 8, pack4f(d1.x,d1.y,d1.z,d1.w));
            aput(As,1536,m,192+u0+16, pack4f(d2.x,d2.y,d2.z,d2.w));
            aput(As,1536,m,192+u0+24, pack4f(d3.x,d3.y,d3.z,d3.w));
            aput(As,1536,m,192+u0+32, pack4f(d4.x,d4.y,d4.z,d4.w));
            aput(As,1536,m,192+u0+40, pack4f(d5.x,d5.y,d5.z,d5.w));
            aput(As,1536,m,192+u0+48, pack4f(d6.x,d6.y,d6.z,d6.w));
            aput(As,1536,m,192+u0+56, pack4f(d7.x,d7.y,d7.z,d7.w));
          }
        }
      }
      __syncthreads();
      f4 acc[2][2];
      #pragma unroll
      for (int i = 0; i < 2; i++)
        #pragma unroll
        for (int mt = 0; mt < 2; mt++) acc[i][mt] = f4{0.f,0.f,0.f,0.f};
      for (int kb = 0; kb < 48; kb++){
        short8 af[2];
        #pragma unroll
        for (int mt = 0; mt < 2; mt++) af[mt] = afrag(As, 1536, mt*16 + c16, kb, q4);
        #pragma unroll
        for (int i = 0; i < 2; i++){
          int nt = ng*8 + wv*2 + i;
          short8 bf = *(const short8*)(p.Whhih_s + ((size_t)(kb*192 + nt))*512 + lane*8);
          #pragma unroll
          for (int mt = 0; mt < 2; mt++) acc[i][mt] = mfma16(af[mt], bf, acc[i][mt]);
        }
      }
      #pragma unroll
      for (int i = 0; i < 2; i++){
        int n = (ng*8 + wv*2 + i)*16 + c16;
        #pragma unroll
        for (int mt = 0; mt < 2; mt++)
          #pragma unroll
          for (int r = 0; r < 4; r++){
            int b = b0 + mt*16 + q4*4 + r;
            cstf(p.gatesHX + (size_t)b*3072 + n, acc[i][mt][r]);
          }
      }
    }
    e++; gsync(p.flags, p.gen, e);

    // ---------- PB ----------
    if (blk < 48){
      const int mh = blk & 1, jjg = blk >> 1;
      const int b0 = mh*32;
      {
        int m = tid0 >> 3, j = tid0 & 7;
        const u64t* src = (const u64t*)(p.ctxb + (size_t)(b0+m)*1536);
        #pragma unroll
        for (int g = 0; g < 6; g++){
          u64t d0,d1,d2,d3,d4,d5,d6,d7;
          int u0 = j + 8*(g*8);
          cldx2_8(d0,d1,d2,d3,d4,d5,d6,d7,
                  src+u0, src+u0+8, src+u0+16, src+u0+24,
                  src+u0+32, src+u0+40, src+u0+48, src+u0+56);
          aput(As,1536,m,u0,    d0); aput(As,1536,m,u0+ 8,d1);
          aput(As,1536,m,u0+16, d2); aput(As,1536,m,u0+24,d3);
          aput(As,1536,m,u0+32, d4); aput(As,1536,m,u0+40,d5);
          aput(As,1536,m,u0+48, d6); aput(As,1536,m,u0+56,d7);
        }
      }
      __syncthreads();
      const int jjt = jjg*2 + (wv & 1), mt = wv >> 1;
      f4 acc[4];
      #pragma unroll
      for (int g = 0; g < 4; g++) acc[g] = f4{0.f,0.f,0.f,0.f};
      for (int kb = 0; kb < 48; kb++){
        short8 af = afrag(As, 1536, mt*16 + c16, kb, q4);
        #pragma unroll
        for (int g = 0; g < 4; g++){
          short8 bf = *(const short8*)(p.Wcomb_s + ((size_t)(kb*192 + g*48 + jjt))*512 + lane*8);
          acc[g] = mfma16(af, bf, acc[g]);
        }
      }
      const int jj = jjt*16 + c16;
      float bfw[4];
      #pragma unroll
      for (int g = 0; g < 4; g++) bfw[g] = p.bfW[g*768 + jj];
      // batched coherent read of gatesHX (16 scattered dwords, 2 waits)
      float gx[16];
      {
        const float* a[16];
        #pragma unroll
        for (int r = 0; r < 4; r++){
          int b = b0 + mt*16 + q4*4 + r;
          size_t g0 = (size_t)b*3072 + jj;
          a[r*4+0] = p.gatesHX + g0;        a[r*4+1] = p.gatesHX + g0 + 768;
          a[r*4+2] = p.gatesHX + g0 + 1536; a[r*4+3] = p.gatesHX + g0 + 2304;
        }
        cldd8(gx[0],gx[1],gx[2],gx[3],gx[4],gx[5],gx[6],gx[7],
              a[0],a[1],a[2],a[3],a[4],a[5],a[6],a[7]);
        cldd8(gx[8],gx[9],gx[10],gx[11],gx[12],gx[13],gx[14],gx[15],
              a[8],a[9],a[10],a[11],a[12],a[13],a[14],a[15]);
      }
      #pragma unroll
      for (int r = 0; r < 4; r++){
        int b = b0 + mt*16 + q4*4 + r;
        int pt = p.ping[b*T_ + t];
        bool cond = (pt > 0) && (t > 0);
        size_t g0 = (size_t)b*3072 + jj;
        float gi = p.base[g0]      + gx[r*4+0];
        float gf = p.base[g0+768]  + gx[r*4+1];
        float gg = p.base[g0+1536] + gx[r*4+2];
        float go = p.base[g0+2304] + gx[r*4+3];
        if (cond){
          gi += acc[0][r] + bfw[0]; gf += acc[1][r] + bfw[1];
          gg += acc[2][r] + bfw[2]; go += acc[3][r] + bfw[3];
        }
        float co = p.cbuf[b*768 + jj];
        float cn = sigm(gf)*co + sigm(gi)*tanh_(gg);
        float hh = sigm(go)*tanh_(cn);
        p.out[((size_t)(t*64 + b))*768 + jj] = hh;
        p.cbuf[b*768 + jj] = cn;
        float hp = __shfl_xor(hh, 1);
        if (!(c16 & 1))
          cst32((u32t*)(p.hB + (size_t)b*768 + jj), (u32t)f2b(hh) | ((u32t)f2b(hp) << 16));
        if (t == T_-1){
          p.out[HALL + b*768 + jj] = hh;
          p.out[HALL + 49152 + b*768 + jj] = cn;
        }
      }
    } else {
      const int local = blk - 48, mh = local & 1, ng = local >> 1;
      const int b0 = mh*32;
      {
        int m = tid0 >> 3, j = tid0 & 7;
        const u64t* src = (const u64t*)(p.ctxb + (size_t)(b0+m)*1536);
        #pragma unroll
        for (int g = 0; g < 6; g++){
          u64t d0,d1,d2,d3,d4,d5,d6,d7;
          int u0 = j + 8*(g*8);
          cldx2_8(d0,d1,d2,d3,d4,d5,d6,d7,
                  src+u0, src+u0+8, src+u0+16, src+u0+24,
                  src+u0+32, src+u0+40, src+u0+48, src+u0+56);
          aput(As,1536,m,u0,    d0); aput(As,1536,m,u0+ 8,d1);
          aput(As,1536,m,u0+16, d2); aput(As,1536,m,u0+24,d3);
          aput(As,1536,m,u0+32, d4); aput(As,1536,m,u0+40,d5);
          aput(As,1536,m,u0+48, d6); aput(As,1536,m,u0+56,d7);
        }
      }
      __syncthreads();
      const int nt = ng*4 + wv;
      f4 acc[2];
      #pragma unroll
      for (int mt = 0; mt < 2; mt++) acc[mt] = f4{0.f,0.f,0.f,0.f};
      for (int kb = 0; kb < 48; kb++){
        short8 bf = *(const short8*)(p.Wfuse_s + ((size_t)(kb*48 + nt))*512 + lane*8);
        #pragma unroll
        for (int mt = 0; mt < 2; mt++){
          short8 af = afrag(As, 1536, mt*16 + c16, kb, q4);
          acc[mt] = mfma16(af, bf, acc[mt]);
        }
      }
      const int n = nt*16 + c16;
      const float bias = p.bfuse[n];
      #pragma unroll
      for (int mt = 0; mt < 2; mt++)
        #pragma unroll
        for (int r = 0; r < 4; r++){
          int b = b0 + mt*16 + q4*4 + r;
          int pt = p.ping[b*T_ + t];
          if (pt > 0 && t > 0)
            cstf(p.x + ((size_t)(t*64 + b))*768 + n, acc[mt][r] + bias);
        }
    }
    e++; gsync(p.flags, p.gen, e);
  }
}

extern "C" void kernel_launch(void* const* d_in, const int* in_sizes, int n_in,
                              void* d_out, int out_size, void* d_ws, size_t ws_size,
                              hipStream_t stream)
{
  (void)in_sizes; (void)n_in; (void)out_size; (void)ws_size;
  char* ws = (char*)d_ws;
  size_t off = 0;
  auto take = [&](size_t bytes)->void*{
    void* ptr = ws + off;
    off += (bytes + 255) & ~(size_t)255;
    return ptr;
  };

  Params p;
  p.question = (const float*)d_in[0];
  p.answer   = (const float*)d_in[1];
  p.x        = (float*)d_in[2];
  p.ping     = (const int*)d_in[3];
  p.h0  = (const float*)d_in[4];  p.c0  = (const float*)d_in[5];
  p.Wqh = (const float*)d_in[6];  p.bqh = (const float*)d_in[7];
  p.Wah = (const float*)d_in[8];  p.bah = (const float*)d_in[9];
  p.Wih = (const float*)d_in[10]; p.bih = (const float*)d_in[11];
  p.Whh = (const float*)d_in[12]; p.bhh = (const float*)d_in[13];
  p.Wq  = (const float*)d_in[14]; p.bq  = (const float*)d_in[15];
  p.Wk  = (const float*)d_in[16]; p.bk  = (const float*)d_in[17];
  p.Wv  = (const float*)d_in[18]; p.bv  = (const float*)d_in[19];
  p.Wfuse = (const float*)d_in[20]; p.bfuse = (const float*)d_in[21];
  p.out = (float*)d_out;

  u32t* sync = (u32t*)take(16384);
  p.flags = sync;
  p.gen   = sync + 3072;

  p.Wqkv_s   = (u16t*)take((size_t)221184*16);
  p.Whhih_s  = (u16t*)take((size_t)589824*16);
  p.Wfuse_s  = (u16t*)take((size_t)147456*16);
  p.Wcomb_s  = (u16t*)take((size_t)589824*16);
  p.Wfuse_bf = (u16t*)take((size_t)1536*768*2);
  p.base     = (float*)take((size_t)64*3072*4);
  p.gatesHX  = (float*)take((size_t)64*3072*4);
  p.ctxb     = (u16t*)take((size_t)64*1536*2);
  p.hB       = (u16t*)take((size_t)64*768*2);
  p.cbuf     = (float*)take((size_t)64*768*4);
  p.bfW      = (float*)take((size_t)3072*4);

  hipFuncSetAttribute(reinterpret_cast<const void*>(sqac_kernel),
                      hipFuncAttributeMaxDynamicSharedMemorySize, 98304);
  hipMemsetAsync(sync, 0, 16384, stream);
  hipLaunchKernelGGL(sqac_kernel, dim3(NBLK), dim3(NTHR), 98304, stream, p);
}